// Round 4
// baseline (194.024 us; speedup 1.0000x reference)
//
#include <hip/hip_runtime.h>
#include <stdint.h>

#define IN_F   4096
#define R_DIM  128
#define OUT_D  4096
#define BSZ    8
#define SEQ    2048
#define M1     (BSZ * SEQ)   /* 16384 */
#define SCALE  2.0f
#define KSPLIT 4
#define KCHUNK (IN_F / KSPLIT)   /* 1024 */
#define NT     (KCHUNK / 64)     /* 16 K-steps per block */

typedef __attribute__((ext_vector_type(8))) short short8;
typedef __attribute__((ext_vector_type(4))) float f32x4;

// ---- native bf16 conversion (compiler emits v_cvt_pk_bf16_f32) ----
static __device__ __forceinline__ unsigned short bf16_1(float f) {
    union { __bf16 h; unsigned short u; } v; v.h = (__bf16)f; return v.u;
}
static __device__ __forceinline__ uint32_t pack2(float a, float b) {
    union { __bf16 h[2]; uint32_t u; } v;
    v.h[0] = (__bf16)a; v.h[1] = (__bf16)b;
    return v.u;
}
static __device__ __forceinline__ float bf16_to_f32(unsigned short h) {
    union { uint32_t u; float f; } v; v.u = ((uint32_t)h) << 16;
    return v.f;
}
static __device__ __forceinline__ int swz16(int r) { return ((r >> 2) ^ r) & 15; }

// ================= Pass 1 v3: A (x) direct global->reg, B (Wd) LDS dbuf =================
struct AF { float4 a0, a1, a2, a3; };

static __device__ __forceinline__ AF load_A(const float* p) {
    AF r;
    r.a0 = *(const float4*)(p);
    r.a1 = *(const float4*)(p + 4);
    r.a2 = *(const float4*)(p + 32);
    r.a3 = *(const float4*)(p + 36);
    return r;
}
static __device__ __forceinline__ void cvt_A(const AF& a, short8& f0, short8& f1) {
    uint32_t* u0 = (uint32_t*)&f0;
    uint32_t* u1 = (uint32_t*)&f1;
    u0[0] = pack2(a.a0.x, a.a0.y); u0[1] = pack2(a.a0.z, a.a0.w);
    u0[2] = pack2(a.a1.x, a.a1.y); u0[3] = pack2(a.a1.z, a.a1.w);
    u1[0] = pack2(a.a2.x, a.a2.y); u1[1] = pack2(a.a2.z, a.a2.w);
    u1[2] = pack2(a.a3.x, a.a3.y); u1[3] = pack2(a.a3.z, a.a3.w);
}
static __device__ __forceinline__ void load_B(float4* rb, const float* p) {
#pragma unroll
    for (int i = 0; i < 8; ++i) rb[i] = *(const float4*)(p + i * 4);
}
static __device__ __forceinline__ void stage_B(const float4* rb, unsigned short* bs,
                                               int brow, int bhalf) {
#pragma unroll
    for (int c = 0; c < 4; ++c) {
        uint4 q;
        q.x = pack2(rb[2 * c].x, rb[2 * c].y);
        q.y = pack2(rb[2 * c].z, rb[2 * c].w);
        q.z = pack2(rb[2 * c + 1].x, rb[2 * c + 1].y);
        q.w = pack2(rb[2 * c + 1].z, rb[2 * c + 1].w);
        const int slot = (bhalf * 4 + c) ^ (brow & 7);
        *(uint4*)&bs[brow * 64 + slot * 8] = q;
    }
}
static __device__ __forceinline__ void compute_step(const unsigned short* bs,
                                                    const AF& acur, f32x4* acc, int lane) {
    short8 af0, af1;
    cvt_A(acur, af0, af1);
    const int l7 = lane & 7;
    const int g  = lane >> 4;
    const int cl = lane & 15;
#pragma unroll
    for (int kki = 0; kki < 2; ++kki) {
        const int chunk = kki * 4 + g;
        const short8 af = kki ? af1 : af0;
#pragma unroll
        for (int nf = 0; nf < 8; ++nf) {
            const int col = nf * 16 + cl;
            const short8 bf = *(const short8*)&bs[col * 64 + ((chunk ^ l7) * 8)];
            acc[nf] = __builtin_amdgcn_mfma_f32_16x16x32_bf16(af, bf, acc[nf], 0, 0, 0);
        }
    }
}

__global__ __launch_bounds__(256, 4) void k_down_v3(const float* __restrict__ x,
                                                    const float* __restrict__ Wd,
                                                    unsigned short* __restrict__ part) {
    __shared__ unsigned short Bs[2][R_DIM * 64];   // 2 x 16 KB, swizzled 16B chunks

    const int tid  = threadIdx.x;
    const int lane = tid & 63;
    const int w    = tid >> 6;               // 0..3
    const int mt   = blockIdx.x & 255;       // 256 m-tiles of 64 rows
    const int ks   = blockIdx.x >> 8;        // 0..3
    const int row0 = mt * 64;
    const int kbeg = ks * KCHUNK;

    f32x4 acc[8];
#pragma unroll
    for (int nf = 0; nf < 8; ++nf)
#pragma unroll
        for (int j = 0; j < 4; ++j) acc[nf][j] = 0.0f;

    // A: each wave owns 16 rows; lane -> (row = lane&15, k-chunk = lane>>4)
    const int arow_g = row0 + w * 16 + (lane & 15);
    const float* asrc = x + (size_t)arow_g * IN_F + kbeg + (lane >> 4) * 8;

    // B staging: thread -> Wd row (output col) tid>>1, k-half (tid&1)*32
    const int brow  = tid >> 1;
    const int bhalf = tid & 1;
    const float* wsrc = Wd + (size_t)brow * IN_F + kbeg + bhalf * 32;

    float4 rbB[8];
    AF a_even, a_odd;

    // prologue
    load_B(rbB, wsrc);                 // t=0
    stage_B(rbB, &Bs[0][0], brow, bhalf);
    load_B(rbB, wsrc + 64);            // t=1
    a_even = load_A(asrc);             // t=0
    __syncthreads();

#define DSTEP(T, ACUR, ANEXT)                                         \
    do {                                                              \
        if ((T) + 1 < NT) ANEXT = load_A(asrc + ((T) + 1) * 64);      \
        if ((T) + 1 < NT) stage_B(rbB, &Bs[((T) + 1) & 1][0], brow, bhalf); \
        if ((T) + 2 < NT) load_B(rbB, wsrc + ((T) + 2) * 64);         \
        compute_step(&Bs[(T) & 1][0], ACUR, acc, lane);               \
        __syncthreads();                                              \
    } while (0)

    for (int t = 0; t < NT; t += 2) {
        DSTEP(t, a_even, a_odd);
        DSTEP(t + 1, a_odd, a_even);
    }
#undef DSTEP

    // epilogue: write bf16 partials
    unsigned short* dst = part + (size_t)ks * M1 * R_DIM;
    const int orow = row0 + w * 16 + ((lane >> 4) << 2);
    const int ocol = lane & 15;
#pragma unroll
    for (int nf = 0; nf < 8; ++nf)
#pragma unroll
        for (int j = 0; j < 4; ++j)
            dst[(size_t)(orow + j) * R_DIM + nf * 16 + ocol] = bf16_1(acc[nf][j]);
}

// ---------------- Reduce: down = sum_ks part[ks] (bf16) ----------------
__global__ __launch_bounds__(512) void k_reduce(const unsigned short* __restrict__ part,
                                                unsigned short* __restrict__ down) {
    const size_t chunk = (size_t)blockIdx.x * 512 + threadIdx.x;
    const size_t off = chunk * 8;
    if (off >= (size_t)M1 * R_DIM) return;
    uint4 p0 = *(const uint4*)(part + off);
    uint4 p1 = *(const uint4*)(part + (size_t)1 * M1 * R_DIM + off);
    uint4 p2 = *(const uint4*)(part + (size_t)2 * M1 * R_DIM + off);
    uint4 p3 = *(const uint4*)(part + (size_t)3 * M1 * R_DIM + off);
    uint4 r;
    const uint32_t* a = (const uint32_t*)&p0;
    const uint32_t* b = (const uint32_t*)&p1;
    const uint32_t* c = (const uint32_t*)&p2;
    const uint32_t* d = (const uint32_t*)&p3;
    uint32_t* o = (uint32_t*)&r;
#pragma unroll
    for (int i = 0; i < 4; ++i) {
        float lo = bf16_to_f32((unsigned short)(a[i] & 0xFFFF)) + bf16_to_f32((unsigned short)(b[i] & 0xFFFF))
                 + bf16_to_f32((unsigned short)(c[i] & 0xFFFF)) + bf16_to_f32((unsigned short)(d[i] & 0xFFFF));
        float hi = bf16_to_f32((unsigned short)(a[i] >> 16)) + bf16_to_f32((unsigned short)(b[i] >> 16))
                 + bf16_to_f32((unsigned short)(c[i] >> 16)) + bf16_to_f32((unsigned short)(d[i] >> 16));
        o[i] = pack2(lo, hi);
    }
    *(uint4*)(down + off) = r;
}

// ---------------- Fallback pass 1 (no split; only if ws too small) ----------------
#define BM1 64
#define BK1 64
#define PAD 8
static __device__ __forceinline__ void st_bf16x4(unsigned short* p, float4 v) {
    uint2 q; q.x = pack2(v.x, v.y); q.y = pack2(v.z, v.w);
    *(uint2*)p = q;
}

__global__ __launch_bounds__(512) void k_down(const float* __restrict__ x,
                                              const float* __restrict__ Wd,
                                              unsigned short* __restrict__ down) {
    __shared__ unsigned short As[BM1][BK1 + PAD];
    __shared__ unsigned short Bsh[R_DIM][BK1 + PAD];

    const int tid  = threadIdx.x;
    const int lane = tid & 63;
    const int w    = tid >> 6;
    const int wm   = w >> 2;
    const int wn   = w & 3;
    const int row0 = blockIdx.x * BM1;

    f32x4 acc[2][2];
#pragma unroll
    for (int m = 0; m < 2; ++m)
#pragma unroll
        for (int n = 0; n < 2; ++n)
#pragma unroll
            for (int j = 0; j < 4; ++j) acc[m][n][j] = 0.0f;

    const int arow = tid >> 4;
    const int acol = (tid & 15) << 2;
    float4 ra[2], rb[4];

    ra[0] = *(const float4*)(x + (size_t)(row0 + arow) * IN_F + acol);
    ra[1] = *(const float4*)(x + (size_t)(row0 + arow + 32) * IN_F + acol);
#pragma unroll
    for (int i = 0; i < 4; ++i)
        rb[i] = *(const float4*)(Wd + (size_t)(arow + 32 * i) * IN_F + acol);
    st_bf16x4(&As[arow][acol], ra[0]);
    st_bf16x4(&As[arow + 32][acol], ra[1]);
#pragma unroll
    for (int i = 0; i < 4; ++i) st_bf16x4(&Bsh[arow + 32 * i][acol], rb[i]);
    __syncthreads();

    for (int k0 = BK1; k0 <= IN_F; k0 += BK1) {
        const bool more = (k0 < IN_F);
        if (more) {
            ra[0] = *(const float4*)(x + (size_t)(row0 + arow) * IN_F + k0 + acol);
            ra[1] = *(const float4*)(x + (size_t)(row0 + arow + 32) * IN_F + k0 + acol);
#pragma unroll
            for (int i = 0; i < 4; ++i)
                rb[i] = *(const float4*)(Wd + (size_t)(arow + 32 * i) * IN_F + k0 + acol);
        }
#pragma unroll
        for (int kk = 0; kk < BK1; kk += 32) {
            short8 af[2], bfv[2];
#pragma unroll
            for (int m = 0; m < 2; ++m)
                af[m] = *(const short8*)&As[wm * 32 + m * 16 + (lane & 15)][kk + (lane >> 4) * 8];
#pragma unroll
            for (int n = 0; n < 2; ++n)
                bfv[n] = *(const short8*)&Bsh[wn * 32 + n * 16 + (lane & 15)][kk + (lane >> 4) * 8];
#pragma unroll
            for (int m = 0; m < 2; ++m)
#pragma unroll
                for (int n = 0; n < 2; ++n)
                    acc[m][n] = __builtin_amdgcn_mfma_f32_16x16x32_bf16(af[m], bfv[n], acc[m][n], 0, 0, 0);
        }
        __syncthreads();
        if (more) {
            st_bf16x4(&As[arow][acol], ra[0]);
            st_bf16x4(&As[arow + 32][acol], ra[1]);
#pragma unroll
            for (int i = 0; i < 4; ++i) st_bf16x4(&Bsh[arow + 32 * i][acol], rb[i]);
            __syncthreads();
        }
    }

#pragma unroll
    for (int m = 0; m < 2; ++m)
#pragma unroll
        for (int n = 0; n < 2; ++n)
#pragma unroll
            for (int j = 0; j < 4; ++j) {
                int r = row0 + wm * 32 + m * 16 + ((lane >> 4) << 2) + j;
                int c = wn * 32 + n * 16 + (lane & 15);
                down[(size_t)r * R_DIM + c] = bf16_1(acc[m][n][j]);
            }
}

// ---------------- Pass 2: out[b][2048][4096] = down[b] @ graph_rep[b] * SCALE ----------------
#define BM2 64
#define BN2 128

__global__ __launch_bounds__(512) void k_out(const unsigned short* __restrict__ down,
                                             const float* __restrict__ g,
                                             float* __restrict__ out) {
    __shared__ unsigned short As[BM2 * R_DIM];
    __shared__ unsigned short Bsv[BN2 * R_DIM];

    const int tid  = threadIdx.x;
    const int lane = tid & 63;
    const int w    = tid >> 6;
    const int wm   = w >> 2;
    const int wn   = w & 3;
    const int blk  = blockIdx.x;
    const int o_t  = blk & 31;
    const int s_t  = (blk >> 5) & 31;
    const int b    = blk >> 10;
    const int s0   = s_t * BM2;
    const int o0   = o_t * BN2;

    {
        const int rr = tid >> 4;
        const int j  = tid & 15;
        const int sl0 = j ^ swz16(rr);
        const int sl1 = j ^ swz16(rr + 32);
        *(uint4*)&As[rr * R_DIM + sl0 * 8] =
            *(const uint4*)(down + ((size_t)(b * SEQ + s0 + rr) * R_DIM) + j * 8);
        *(uint4*)&As[(rr + 32) * R_DIM + sl1 * 8] =
            *(const uint4*)(down + ((size_t)(b * SEQ + s0 + rr + 32) * R_DIM) + j * 8);
    }
    {
        const int oq  = tid & 31;
        const int kq0 = tid >> 5;
#pragma unroll
        for (int rep = 0; rep < 2; ++rep) {
            const int kq = kq0 + 16 * rep;
            float4 v0 = *(const float4*)(g + ((size_t)b * R_DIM + 4 * kq + 0) * OUT_D + o0 + 4 * oq);
            float4 v1 = *(const float4*)(g + ((size_t)b * R_DIM + 4 * kq + 1) * OUT_D + o0 + 4 * oq);
            float4 v2 = *(const float4*)(g + ((size_t)b * R_DIM + 4 * kq + 2) * OUT_D + o0 + 4 * oq);
            float4 v3 = *(const float4*)(g + ((size_t)b * R_DIM + 4 * kq + 3) * OUT_D + o0 + 4 * oq);
            const float* p0 = (const float*)&v0;
            const float* p1 = (const float*)&v1;
            const float* p2 = (const float*)&v2;
            const float* p3 = (const float*)&v3;
#pragma unroll
            for (int i = 0; i < 4; ++i) {
                const int o = 4 * oq + i;
                uint2 q;
                q.x = pack2(p0[i], p1[i]);
                q.y = pack2(p2[i], p3[i]);
                const int slot = (kq >> 1) ^ swz16(o);
                *(uint2*)&Bsv[o * R_DIM + slot * 8 + (kq & 1) * 4] = q;
            }
        }
    }
    __syncthreads();

    f32x4 acc[2][2];
#pragma unroll
    for (int m = 0; m < 2; ++m)
#pragma unroll
        for (int n = 0; n < 2; ++n)
#pragma unroll
            for (int j = 0; j < 4; ++j) acc[m][n][j] = 0.0f;

#pragma unroll
    for (int kk = 0; kk < R_DIM; kk += 32) {
        const int cbase = (kk >> 3) + (lane >> 4);
        short8 af[2], bfv[2];
#pragma unroll
        for (int m = 0; m < 2; ++m) {
            const int r = wm * 32 + m * 16 + (lane & 15);
            af[m] = *(const short8*)&As[r * R_DIM + (cbase ^ swz16(r)) * 8];
        }
#pragma unroll
        for (int n = 0; n < 2; ++n) {
            const int o = wn * 32 + n * 16 + (lane & 15);
            bfv[n] = *(const short8*)&Bsv[o * R_DIM + (cbase ^ swz16(o)) * 8];
        }
#pragma unroll
        for (int m = 0; m < 2; ++m)
#pragma unroll
            for (int n = 0; n < 2; ++n)
                acc[m][n] = __builtin_amdgcn_mfma_f32_16x16x32_bf16(af[m], bfv[n], acc[m][n], 0, 0, 0);
    }

#pragma unroll
    for (int m = 0; m < 2; ++m)
#pragma unroll
        for (int n = 0; n < 2; ++n)
#pragma unroll
            for (int j = 0; j < 4; ++j) {
                int s = s0 + wm * 32 + m * 16 + ((lane >> 4) << 2) + j;
                int o = o0 + wn * 32 + n * 16 + (lane & 15);
                out[((size_t)b * SEQ + s) * OUT_D + o] = SCALE * acc[m][n][j];
            }
}

extern "C" void kernel_launch(void* const* d_in, const int* in_sizes, int n_in,
                              void* d_out, int out_size, void* d_ws, size_t ws_size,
                              hipStream_t stream) {
    const float* graph_rep = (const float*)d_in[0];
    const float* x         = (const float*)d_in[1];
    const float* Wd        = (const float*)d_in[2];
    float* out             = (float*)d_out;

    const size_t down_elems = (size_t)M1 * R_DIM;
    const size_t need_split = (KSPLIT + 1) * down_elems * sizeof(unsigned short);

    if (ws_size >= need_split) {
        unsigned short* part = (unsigned short*)d_ws;
        unsigned short* down = part + (size_t)KSPLIT * down_elems;
        k_down_v3<<<(M1 / 64) * KSPLIT, 256, 0, stream>>>(x, Wd, part);
        k_reduce<<<(int)((down_elems / 8 + 511) / 512), 512, 0, stream>>>(part, down);
        k_out<<<BSZ * (SEQ / BM2) * (OUT_D / BN2), 512, 0, stream>>>(down, graph_rep, out);
    } else {
        unsigned short* down = (unsigned short*)d_ws;
        k_down<<<M1 / BM1, 512, 0, stream>>>(x, Wd, down);
        k_out<<<BSZ * (SEQ / BM2) * (OUT_D / BN2), 512, 0, stream>>>(down, graph_rep, out);
    }
}